// Round 8
// baseline (1131.889 us; speedup 1.0000x reference)
//
#include <hip/hip_runtime.h>

// RetinaNet head via bf16 MFMA implicit-GEMM (16x16x32) — R9 structure.
// R9 = R8 (row-pair segments, XCD cb-stacking swizzle, R1 sync core) with
// W READ DIRECTLY FROM GLOBAL (L2-hot) INTO REGISTERS — no W LDS staging,
// no W ds_reads. Rationale (R8 post-mortem): LDS pipe (72KB writes + 480KB
// reads per CU-chunk-pair) was co-saturated with MFMA (~5.6K cyc each),
// capping MfmaUtil ~35-40%. W blob layout already matches per-lane fragment
// order -> afr = wchunk[(tap*4+q)*64 + cc*16 + n16] is a coalesced 16B/lane
// global load; W is 36KB/chunk, shared by ALL blocks (cb-stacked siblings on
// the same XCD keep it L2-hot). LDS now holds only X (36,864B) ->
// __launch_bounds__(256,3): 3 blocks/CU, 12 waves, hides the ~200cyc L2
// latency of W loads. LDS traffic drops 4.6x; MFMA becomes the longest pipe.

typedef __attribute__((ext_vector_type(8))) short short8;
typedef __attribute__((ext_vector_type(4))) float floatx4;

#define LVLTOT 14143  // sum of padded (H+2)(W+2) over 5 levels

__device__ __forceinline__ unsigned short f2bf(float f) {
  unsigned int u = __float_as_uint(f);
  unsigned int r = (u + 0x7fffu + ((u >> 16) & 1u)) >> 16;
  return (unsigned short)r;
}

__device__ __forceinline__ void gload_lds16(const void* g, void* l) {
  __builtin_amdgcn_global_load_lds(
      (const __attribute__((address_space(1))) unsigned int*)g,
      (__attribute__((address_space(3))) unsigned int*)l, 16, 0, 0);
}

// ================= fused prep: xprep + wprep + border zero =================
// (unchanged from R7/R8)
struct PrepArgs {
  const float* f[5];
  const float* w[10];
  unsigned short* wdst[10];
  int wblk_off[11];
  int cout[10];
  unsigned short* x0;
  unsigned short* bufA;
  unsigned short* bufB;
};

__global__ __launch_bounds__(256) void prep(PrepArgs A) {
  static const int Ht[5] = {100, 50, 25, 13, 7};
  static const int Wpt[5] = {102, 52, 27, 15, 9};
  static const int LOFFt[5] = {0, 10404, 13108, 13837, 14062};
  __shared__ float ts[32][33];
  const int bid = blockIdx.x;
  const int t = threadIdx.x;

  if (bid < 1090) {
    // ---- xprep: one 32-px row-strip, all 256 ch, one n ----
    int sid = bid % 545, n = bid / 545;
    int l, h, wb;
    if (sid < 400)      { l = 0; h = sid >> 2; wb = sid & 3; }
    else if (sid < 500) { l = 1; h = (sid - 400) >> 1; wb = (sid - 400) & 1; }
    else if (sid < 525) { l = 2; h = sid - 500; wb = 0; }
    else if (sid < 538) { l = 3; h = sid - 525; wb = 0; }
    else                { l = 4; h = sid - 538; wb = 0; }
    const float* f = A.f[l];
    int H = Ht[l], W = H, Wp = Wpt[l], loff = LOFFt[l];
    int w0 = wb * 32;
    for (int s = 0; s < 8; s++) {
      int ch0 = s * 32;
      __syncthreads();
#pragma unroll
      for (int r4 = 0; r4 < 4; r4++) {
        int ch = ch0 + (t >> 5) + r4 * 8;
        int px = w0 + (t & 31);
        float v = 0.f;
        if (px < W) v = f[(((size_t)n * 256 + ch) * H + h) * W + px];
        ts[(t >> 5) + r4 * 8][t & 31] = v;
      }
      __syncthreads();
      int pxl = t >> 3, c4 = t & 7;
      if (w0 + pxl < W) {
        unsigned short pk[4];
#pragma unroll
        for (int k = 0; k < 4; k++) pk[k] = f2bf(ts[c4 * 4 + k][pxl]);
        *(unsigned long long*)(A.x0 +
            ((size_t)n * LVLTOT + loff + (size_t)(h + 1) * Wp + (w0 + pxl + 1)) *
                256 + ch0 + c4 * 4) = *(unsigned long long*)pk;
      }
    }
    return;
  }

  if (bid < 3970) {
    // ---- wprep: block = one padded co of one tensor; thread = ci ----
    // Layout: [cb][chunk(ci>>5)][tap][qd][co64][8]
    int b2 = bid - 1090;
    int tix = 0;
    while (b2 >= A.wblk_off[tix + 1]) tix++;
    int co = b2 - A.wblk_off[tix];
    int ci = t;
    bool valid = co < A.cout[tix];
    const float* w = A.w[tix];
    unsigned short* dst = A.wdst[tix];
    int cb = co >> 6, col = co & 63, chk = ci >> 5, qd = (ci >> 3) & 3, j = ci & 7;
#pragma unroll
    for (int tap = 0; tap < 9; tap++) {
      float v = valid ? w[((size_t)co * 256 + ci) * 9 + tap] : 0.f;
      dst[((((size_t)(cb * 8 + chk) * 9 + tap) * 4 + qd) * 64 + col) * 8 + j] =
          f2bf(v);
    }
    return;
  }

  // ---- border zero: items = 800 border px x 32 octs per plane ----
  {
    static const int BCUM[6] = {0, 404, 608, 712, 768, 800};
    int b3 = bid - 3970;             // [0,800): plane = b3/100
    int plane = b3 / 100;
    int item = (b3 % 100) * 256 + t; // [0,25600)
    int pxi = item >> 5, oct = item & 31;
    if (pxi >= 800) return;
    int l = 0;
    while (pxi >= BCUM[l + 1]) l++;
    int j = pxi - BCUM[l];
    int Wp = Wpt[l];
    int r, c;
    if (j < Wp)            { r = 0; c = j; }
    else if (j < 2 * Wp)   { r = Wp - 1; c = j - Wp; }
    else { int k = j - 2 * Wp; r = 1 + (k >> 1); c = (k & 1) ? Wp - 1 : 0; }
    size_t px = (size_t)LOFFt[l] + (size_t)r * Wp + c;
    unsigned short* base = (plane < 4)
                               ? (A.bufA + (size_t)plane * LVLTOT * 256)
                               : (A.bufB + (size_t)(plane - 4) * LVLTOT * 256);
    floatx4 z;
    z[0] = z[1] = z[2] = z[3] = 0.f;
    *(floatx4*)(base + px * 256 + oct * 8) = z;
  }
}

// ---- segment decode: seg s -> level, top output row h0 (=2*pair), w0 ----
// Segments per level: l0 50x7=350, l1 25x4=100, l2 13x2=26, l3 7, l4 4.
__device__ __forceinline__ void decode_seg(int s, int& l, int& h0, int& w0,
                                           int& H, int& Wp, int& loff) {
  if (s < 350)      { l = 0; int hp = s / 7; w0 = (s - hp * 7) * 16; h0 = hp * 2;
                      H = 100; Wp = 102; loff = 0; }
  else if (s < 450) { l = 1; int r = s - 350; h0 = (r >> 2) * 2; w0 = (r & 3) * 16;
                      H = 50; Wp = 52; loff = 10404; }
  else if (s < 476) { l = 2; int r = s - 450; h0 = (r >> 1) * 2; w0 = (r & 1) * 16;
                      H = 25; Wp = 27; loff = 13108; }
  else if (s < 483) { l = 3; h0 = (s - 476) * 2; w0 = 0; H = 13; Wp = 15;
                      loff = 13837; }
  else              { l = 4; h0 = (s - 483) * 2; w0 = 0; H = 7; Wp = 9;
                      loff = 14062; }
}

// ---- per-thread X staging source offsets (plane-relative shorts, ci=0) ----
// 2304 16B-units = [q4][seg8][row4][col18]; unit u = k*256 + t; dest linear.
// needs in scope: sblk (segment-block index [0,61))
#define CONV_XPRE()                                                            \
  int xsrc[9];                                                                 \
  _Pragma("unroll") for (int k = 0; k < 9; k++) {                              \
    int u = k * 256 + t;                                                       \
    int qq = u / 576, rem = u - qq * 576;                                      \
    int sl8 = rem / 72, rm2 = rem - sl8 * 72;                                  \
    int r4 = rm2 / 18, c18 = rm2 - r4 * 18;                                    \
    int sg = sblk * 8 + sl8; if (sg > 486) sg = 486;                           \
    int l_, h0_, w0_, H_, Wp_, lo_;                                            \
    decode_seg(sg, l_, h0_, w0_, H_, Wp_, lo_);                                \
    int prow = h0_ + r4; if (prow > H_ + 1) prow = H_ + 1;                     \
    int pcol = w0_ + c18; if (pcol > Wp_ - 1) pcol = Wp_ - 1;                  \
    xsrc[k] = (lo_ + prow * Wp_ + pcol) * 256 + qq * 8;                        \
  }

// ---- K-loop body: X staged to LDS (9 gloads/thread), W read DIRECTLY from
// global (L2) as per-lane coalesced 16B fragments. R1 sync structure.
// needs: t, lane, wv, q, n16, xsrc, lds_x, acc[4][4] ----
#define CONV_MAIN_LOOP(INP, WBLOB, CB)                                         \
  {                                                                            \
    _Pragma("unroll 1") for (int ch = 0; ch < 8; ch++) {                       \
      if (ch) __syncthreads();                                                 \
      _Pragma("unroll") for (int k = 0; k < 9; k++)                            \
        gload_lds16((INP) + xsrc[k] + ch * 32,                                 \
                    lds_x + (size_t)(k * 256 + wv * 64) * 8);                  \
      __syncthreads();                                                         \
      const short8* xw =                                                       \
          (const short8*)((WBLOB) + ((size_t)((CB)*8 + ch)) * 18432);          \
      const short8* xx = (const short8*)lds_x;                                 \
      _Pragma("unroll") for (int tdx = 0; tdx < 3; tdx++) {                    \
        short8 wfr[3][4];                                                      \
        _Pragma("unroll") for (int tdy = 0; tdy < 3; tdy++)                    \
          _Pragma("unroll") for (int cc = 0; cc < 4; cc++)                     \
            wfr[tdy][cc] =                                                     \
                xw[((tdy * 3 + tdx) * 4 + q) * 64 + cc * 16 + n16];            \
        short8 bfr[2][4];                                                      \
        _Pragma("unroll") for (int sb = 0; sb < 2; sb++)                       \
          _Pragma("unroll") for (int r = 0; r < 4; r++)                        \
            bfr[sb][r] =                                                       \
                xx[q * 576 + (wv * 2 + sb) * 72 + r * 18 + tdx + n16];         \
        _Pragma("unroll") for (int tdy = 0; tdy < 3; tdy++) {                  \
          _Pragma("unroll") for (int cc = 0; cc < 4; cc++) {                   \
            _Pragma("unroll") for (int rg = 0; rg < 4; rg++)                   \
              acc[cc][rg] = __builtin_amdgcn_mfma_f32_16x16x32_bf16(           \
                  wfr[tdy][cc], bfr[rg >> 1][(rg & 1) + tdy], acc[cc][rg],     \
                  0, 0, 0);                                                    \
          }                                                                    \
        }                                                                      \
      }                                                                        \
    }                                                                          \
  }

// ---- tower conv layer (bf16 in -> bf16 out, +bias, ReLU) ----
// XCD swizzle: p -> xcd=p&7, j=p>>3; cnt = 31 (xcd<4) else 30;
// j = tlw*4 + cb (cb fastest); tl = tlw*8 + xcd in [0,244);
// sblk = tl % 61, plane = tl / 61.
__global__ __launch_bounds__(256, 3) void conv_tower_mfma(
    const unsigned short* __restrict__ xin, unsigned short* __restrict__ xout,
    const unsigned short* __restrict__ wblob_cls,
    const unsigned short* __restrict__ wblob_box,
    const float* __restrict__ bias_cls, const float* __restrict__ bias_box,
    int in_n_stride, int in_tw_stride) {
  const int p = blockIdx.x;
  const int xcd = p & 7, jj = p >> 3;
  const int cnt = (xcd < 4) ? 31 : 30;
  if (jj >= 4 * cnt) return;
  const int tlw = jj >> 2, cb = jj & 3;
  const int tl = tlw * 8 + xcd;
  const int sblk = tl % 61;
  const int zpl = tl / 61;
  const int n = zpl >> 1, tw = zpl & 1;

  __shared__ __align__(16) unsigned short lds_x[18432];
  const int t = threadIdx.x, lane = t & 63, wv = t >> 6;
  const int q = lane >> 4, n16 = lane & 15;
  const unsigned short* wblob = tw ? wblob_box : wblob_cls;
  const float* bias = tw ? bias_box : bias_cls;
  const unsigned short* inp =
      xin + ((size_t)n * in_n_stride + (size_t)tw * in_tw_stride) * 256;
  unsigned short* outp = xout + ((size_t)(n * 2 + tw) * LVLTOT) * 256;

  floatx4 acc[4][4];
#pragma unroll
  for (int i = 0; i < 4; i++)
#pragma unroll
    for (int jx = 0; jx < 4; jx++) acc[i][jx] = (floatx4){0.f, 0.f, 0.f, 0.f};

  CONV_XPRE()
  CONV_MAIN_LOOP(inp, wblob, cb)

  // epilogue: +bias, relu, bf16, store 4 consecutive channels (8B) per lane
#pragma unroll
  for (int rg = 0; rg < 4; rg++) {
    int sg = sblk * 8 + wv * 2 + (rg >> 1);
    if (sg > 486) sg = 486;
    int l_, h0_, w0_, H_, Wp_, lo_;
    decode_seg(sg, l_, h0_, w0_, H_, Wp_, lo_);
    int h = h0_ + (rg & 1);
    int w_ = w0_ + n16;
    if (h < H_ && w_ < H_) {  // levels are square: W == H
#pragma unroll
      for (int cc = 0; cc < 4; cc++) {
        floatx4 bb = *(const floatx4*)(bias + cb * 64 + cc * 16 + q * 4);
        unsigned short pk[4];
#pragma unroll
        for (int rgi = 0; rgi < 4; rgi++)
          pk[rgi] = f2bf(fmaxf(acc[cc][rg][rgi] + bb[rgi], 0.f));
        size_t base = ((size_t)lo_ + (size_t)(h + 1) * Wp_ + (w_ + 1)) * 256 +
                      cb * 64 + cc * 16 + q * 4;
        *(unsigned long long*)(outp + base) = *(unsigned long long*)pk;
      }
    }
  }
}

// ---- merged final conv (yb<12: cls cb=yb; yb==12: box), permuted fp32 out --
// XCD swizzle: p -> xcd=p&7, j=p>>3; cnt = 16 (xcd<2) else 15;
// j = tlw*13 + yb (yb fastest); tl = tlw*8 + xcd in [0,122);
// sblk = tl % 61, n = tl / 61.
__global__ __launch_bounds__(256, 3) void conv_final_mfma(
    const unsigned short* __restrict__ xin, float* __restrict__ out,
    const unsigned short* __restrict__ wblob_cls,
    const unsigned short* __restrict__ wblob_box,
    const float* __restrict__ bias_cls, const float* __restrict__ bias_box) {
  const int p = blockIdx.x;
  const int xcd = p & 7, jj = p >> 3;
  const int cnt = (xcd < 2) ? 16 : 15;
  if (jj >= 13 * cnt) return;
  const int tlw = jj / 13, yb = jj - tlw * 13;
  const int tl = tlw * 8 + xcd;
  const int sblk = tl % 61;
  const int n = tl / 61;

  __shared__ __align__(16) unsigned short lds_x[18432];
  const int t = threadIdx.x, lane = t & 63, wv = t >> 6;
  const int q = lane >> 4, n16 = lane & 15;
  const bool is_cls = yb < 12;
  const int cb = is_cls ? yb : 0;
  const int tw = is_cls ? 0 : 1;
  const int Cout = is_cls ? 720 : 36;
  const unsigned short* wblob = is_cls ? wblob_cls : wblob_box;
  const float* bias = is_cls ? bias_cls : bias_box;
  const int RB[5] = {0, 90000, 112500, 118125, 119646};
  const unsigned short* inp = xin + ((size_t)(n * 2 + tw) * LVLTOT) * 256;

  floatx4 acc[4][4];
#pragma unroll
  for (int i = 0; i < 4; i++)
#pragma unroll
    for (int jx = 0; jx < 4; jx++) acc[i][jx] = (floatx4){0.f, 0.f, 0.f, 0.f};

  CONV_XPRE()
  CONV_MAIN_LOOP(inp, wblob, cb)

#pragma unroll
  for (int rg = 0; rg < 4; rg++) {
    int sg = sblk * 8 + wv * 2 + (rg >> 1);
    if (sg > 486) sg = 486;
    int l_, h0_, w0_, H_, Wp_, lo_;
    decode_seg(sg, l_, h0_, w0_, H_, Wp_, lo_);
    int h = h0_ + (rg & 1);
    int w_ = w0_ + n16;
    if (h < H_ && w_ < H_) {
      size_t ridx = (size_t)RB[l_] + ((size_t)h * H_ + w_) * 9;
#pragma unroll
      for (int cc = 0; cc < 4; cc++) {
        int co0 = cb * 64 + cc * 16 + q * 4;
        if (co0 >= Cout) continue;
        floatx4 bb = *(const floatx4*)(bias + co0);
        int a = is_cls ? (co0 / 80) : (co0 >> 2);
        int col0 = is_cls ? (co0 - a * 80) : 80;
        floatx4 v;
#pragma unroll
        for (int rgi = 0; rgi < 4; rgi++) v[rgi] = acc[cc][rg][rgi] + bb[rgi];
        *(floatx4*)(out + ((size_t)n * 120087 + ridx + a) * 84 + col0) = v;
      }
    }
  }
}

extern "C" void kernel_launch(void* const* d_in, const int* in_sizes, int n_in,
                              void* d_out, int out_size, void* d_ws,
                              size_t ws_size, hipStream_t stream) {
  // ws layout (bytes):
  //   bufB [0, 28964864)    (X0 aliased to bufB planes 2,3: dead after layer 1)
  //   X0   [14482432, 28964864)
  //   bufA [28964864, 57929728)
  //   tower blobs 8 x 1179648 at 57929728 (cls0..3, box0..3)
  //   cls final blob 3538944 at 67366912; box final blob 294912 at 70905856
  char* ws = (char*)d_ws;
  unsigned short* bufB = (unsigned short*)(ws);
  unsigned short* X0 = (unsigned short*)(ws + 14482432);
  unsigned short* bufA = (unsigned short*)(ws + 28964864);
  unsigned short* tb[8];
  for (int i = 0; i < 8; i++)
    tb[i] = (unsigned short*)(ws + 57929728 + (size_t)i * 1179648);
  unsigned short* fb_cls = (unsigned short*)(ws + 67366912);
  unsigned short* fb_box = (unsigned short*)(ws + 70905856);

  float* out = (float*)d_out;

  PrepArgs pa;
  for (int i = 0; i < 5; i++) pa.f[i] = (const float*)d_in[i];
  for (int i = 0; i < 4; i++) {
    pa.w[i] = (const float*)d_in[5 + 2 * i];       // cls_w0..3
    pa.w[4 + i] = (const float*)d_in[13 + 2 * i];  // box_w0..3
    pa.wdst[i] = tb[i];
    pa.wdst[4 + i] = tb[4 + i];
    pa.cout[i] = pa.cout[4 + i] = 256;
  }
  pa.w[8] = (const float*)d_in[21]; pa.wdst[8] = fb_cls; pa.cout[8] = 720;
  pa.w[9] = (const float*)d_in[23]; pa.wdst[9] = fb_box; pa.cout[9] = 36;
  // padded-co block counts: towers 256 each, cls 768, box 64
  int off = 0;
  for (int i = 0; i < 8; i++) { pa.wblk_off[i] = off; off += 256; }
  pa.wblk_off[8] = off; off += 768;
  pa.wblk_off[9] = off; off += 64;
  pa.wblk_off[10] = off;  // 2880
  pa.x0 = X0;
  pa.bufA = bufA;
  pa.bufB = bufB;

  prep<<<dim3(4770), 256, 0, stream>>>(pa);

  const float *cls_b[4], *box_b[4];
  for (int i = 0; i < 4; i++) {
    cls_b[i] = (const float*)d_in[6 + 2 * i];
    box_b[i] = (const float*)d_in[14 + 2 * i];
  }

  conv_tower_mfma<<<dim3(992), 256, 0, stream>>>(X0, bufA, tb[0], tb[4],
                                                 cls_b[0], box_b[0], LVLTOT, 0);
  conv_tower_mfma<<<dim3(992), 256, 0, stream>>>(
      bufA, bufB, tb[1], tb[5], cls_b[1], box_b[1], 2 * LVLTOT, LVLTOT);
  conv_tower_mfma<<<dim3(992), 256, 0, stream>>>(
      bufB, bufA, tb[2], tb[6], cls_b[2], box_b[2], 2 * LVLTOT, LVLTOT);
  conv_tower_mfma<<<dim3(992), 256, 0, stream>>>(
      bufA, bufB, tb[3], tb[7], cls_b[3], box_b[3], 2 * LVLTOT, LVLTOT);

  conv_final_mfma<<<dim3(1664), 256, 0, stream>>>(
      bufB, out, fb_cls, fb_box, (const float*)d_in[22], (const float*)d_in[24]);
}

// Round 9
// 782.749 us; speedup vs baseline: 1.4460x; 1.4460x over previous
//
#include <hip/hip_runtime.h>

// RetinaNet head via bf16 MFMA implicit-GEMM (16x16x32) — R10 structure.
// R10 = R8 (row-pair segments, XCD cb-stacking swizzle, R1 sync core) with
// W fragments read from GLOBAL (L2-hot) into REGISTERS in three batches of
// 12 (wA/wB before the chunk barrier — their latency folds into the
// existing vmcnt(0) drain that waits for X staging; wC issued under tdx1's
// MFMA cover). This is R9's idea executed with the register budget it
// needs: __launch_bounds__(256,2) gives a 256-VGPR budget so the 12-frag
// batches stay live (R9's (256,3) forced 76 VGPR -> per-MFMA reload stalls,
// 16.5% MfmaUtil). LDS holds only X (36,864B). LDS reads per chunk per wave
// drop 60 -> 24 (the R8-measured wall: LDS-read pipe ~4-5K cyc/CU-chunk vs
// MFMA 1.4K); W streams from L2 (~196KB/CU-chunk, kept hot by cb-stacking).

typedef __attribute__((ext_vector_type(8))) short short8;
typedef __attribute__((ext_vector_type(4))) float floatx4;

#define LVLTOT 14143  // sum of padded (H+2)(W+2) over 5 levels

__device__ __forceinline__ unsigned short f2bf(float f) {
  unsigned int u = __float_as_uint(f);
  unsigned int r = (u + 0x7fffu + ((u >> 16) & 1u)) >> 16;
  return (unsigned short)r;
}

__device__ __forceinline__ void gload_lds16(const void* g, void* l) {
  __builtin_amdgcn_global_load_lds(
      (const __attribute__((address_space(1))) unsigned int*)g,
      (__attribute__((address_space(3))) unsigned int*)l, 16, 0, 0);
}

// ================= fused prep: xprep + wprep + border zero =================
// (unchanged from R7/R8)
struct PrepArgs {
  const float* f[5];
  const float* w[10];
  unsigned short* wdst[10];
  int wblk_off[11];
  int cout[10];
  unsigned short* x0;
  unsigned short* bufA;
  unsigned short* bufB;
};

__global__ __launch_bounds__(256) void prep(PrepArgs A) {
  static const int Ht[5] = {100, 50, 25, 13, 7};
  static const int Wpt[5] = {102, 52, 27, 15, 9};
  static const int LOFFt[5] = {0, 10404, 13108, 13837, 14062};
  __shared__ float ts[32][33];
  const int bid = blockIdx.x;
  const int t = threadIdx.x;

  if (bid < 1090) {
    // ---- xprep: one 32-px row-strip, all 256 ch, one n ----
    int sid = bid % 545, n = bid / 545;
    int l, h, wb;
    if (sid < 400)      { l = 0; h = sid >> 2; wb = sid & 3; }
    else if (sid < 500) { l = 1; h = (sid - 400) >> 1; wb = (sid - 400) & 1; }
    else if (sid < 525) { l = 2; h = sid - 500; wb = 0; }
    else if (sid < 538) { l = 3; h = sid - 525; wb = 0; }
    else                { l = 4; h = sid - 538; wb = 0; }
    const float* f = A.f[l];
    int H = Ht[l], W = H, Wp = Wpt[l], loff = LOFFt[l];
    int w0 = wb * 32;
    for (int s = 0; s < 8; s++) {
      int ch0 = s * 32;
      __syncthreads();
#pragma unroll
      for (int r4 = 0; r4 < 4; r4++) {
        int ch = ch0 + (t >> 5) + r4 * 8;
        int px = w0 + (t & 31);
        float v = 0.f;
        if (px < W) v = f[(((size_t)n * 256 + ch) * H + h) * W + px];
        ts[(t >> 5) + r4 * 8][t & 31] = v;
      }
      __syncthreads();
      int pxl = t >> 3, c4 = t & 7;
      if (w0 + pxl < W) {
        unsigned short pk[4];
#pragma unroll
        for (int k = 0; k < 4; k++) pk[k] = f2bf(ts[c4 * 4 + k][pxl]);
        *(unsigned long long*)(A.x0 +
            ((size_t)n * LVLTOT + loff + (size_t)(h + 1) * Wp + (w0 + pxl + 1)) *
                256 + ch0 + c4 * 4) = *(unsigned long long*)pk;
      }
    }
    return;
  }

  if (bid < 3970) {
    // ---- wprep: block = one padded co of one tensor; thread = ci ----
    // Layout: [cb][chunk(ci>>5)][tap][qd][co64][8]
    int b2 = bid - 1090;
    int tix = 0;
    while (b2 >= A.wblk_off[tix + 1]) tix++;
    int co = b2 - A.wblk_off[tix];
    int ci = t;
    bool valid = co < A.cout[tix];
    const float* w = A.w[tix];
    unsigned short* dst = A.wdst[tix];
    int cb = co >> 6, col = co & 63, chk = ci >> 5, qd = (ci >> 3) & 3, j = ci & 7;
#pragma unroll
    for (int tap = 0; tap < 9; tap++) {
      float v = valid ? w[((size_t)co * 256 + ci) * 9 + tap] : 0.f;
      dst[((((size_t)(cb * 8 + chk) * 9 + tap) * 4 + qd) * 64 + col) * 8 + j] =
          f2bf(v);
    }
    return;
  }

  // ---- border zero: items = 800 border px x 32 octs per plane ----
  {
    static const int BCUM[6] = {0, 404, 608, 712, 768, 800};
    int b3 = bid - 3970;             // [0,800): plane = b3/100
    int plane = b3 / 100;
    int item = (b3 % 100) * 256 + t; // [0,25600)
    int pxi = item >> 5, oct = item & 31;
    if (pxi >= 800) return;
    int l = 0;
    while (pxi >= BCUM[l + 1]) l++;
    int j = pxi - BCUM[l];
    int Wp = Wpt[l];
    int r, c;
    if (j < Wp)            { r = 0; c = j; }
    else if (j < 2 * Wp)   { r = Wp - 1; c = j - Wp; }
    else { int k = j - 2 * Wp; r = 1 + (k >> 1); c = (k & 1) ? Wp - 1 : 0; }
    size_t px = (size_t)LOFFt[l] + (size_t)r * Wp + c;
    unsigned short* base = (plane < 4)
                               ? (A.bufA + (size_t)plane * LVLTOT * 256)
                               : (A.bufB + (size_t)(plane - 4) * LVLTOT * 256);
    floatx4 z;
    z[0] = z[1] = z[2] = z[3] = 0.f;
    *(floatx4*)(base + px * 256 + oct * 8) = z;
  }
}

// ---- segment decode: seg s -> level, top output row h0 (=2*pair), w0 ----
// Segments per level: l0 50x7=350, l1 25x4=100, l2 13x2=26, l3 7, l4 4.
__device__ __forceinline__ void decode_seg(int s, int& l, int& h0, int& w0,
                                           int& H, int& Wp, int& loff) {
  if (s < 350)      { l = 0; int hp = s / 7; w0 = (s - hp * 7) * 16; h0 = hp * 2;
                      H = 100; Wp = 102; loff = 0; }
  else if (s < 450) { l = 1; int r = s - 350; h0 = (r >> 2) * 2; w0 = (r & 3) * 16;
                      H = 50; Wp = 52; loff = 10404; }
  else if (s < 476) { l = 2; int r = s - 450; h0 = (r >> 1) * 2; w0 = (r & 1) * 16;
                      H = 25; Wp = 27; loff = 13108; }
  else if (s < 483) { l = 3; h0 = (s - 476) * 2; w0 = 0; H = 13; Wp = 15;
                      loff = 13837; }
  else              { l = 4; h0 = (s - 483) * 2; w0 = 0; H = 7; Wp = 9;
                      loff = 14062; }
}

// ---- per-thread X staging source offsets (plane-relative shorts, ci=0) ----
// 2304 16B-units = [q4][seg8][row4][col18]; unit u = k*256 + t; dest linear.
// needs in scope: sblk (segment-block index [0,61))
#define CONV_XPRE()                                                            \
  int xsrc[9];                                                                 \
  _Pragma("unroll") for (int k = 0; k < 9; k++) {                              \
    int u = k * 256 + t;                                                       \
    int qq = u / 576, rem = u - qq * 576;                                      \
    int sl8 = rem / 72, rm2 = rem - sl8 * 72;                                  \
    int r4 = rm2 / 18, c18 = rm2 - r4 * 18;                                    \
    int sg = sblk * 8 + sl8; if (sg > 486) sg = 486;                           \
    int l_, h0_, w0_, H_, Wp_, lo_;                                            \
    decode_seg(sg, l_, h0_, w0_, H_, Wp_, lo_);                                \
    int prow = h0_ + r4; if (prow > H_ + 1) prow = H_ + 1;                     \
    int pcol = w0_ + c18; if (pcol > Wp_ - 1) pcol = Wp_ - 1;                  \
    xsrc[k] = (lo_ + prow * Wp_ + pcol) * 256 + qq * 8;                        \
  }

// ---- W fragment batch load (12 frags = one tdx column) from global/L2 ----
// blob chunk = 2304 short8; frag idx = ((tdy*3+tdx)*4+q)*64 + cc*16 + n16
#define WLOAD(DST, XWB, CBASE, TDX)                                            \
  _Pragma("unroll") for (int u = 0; u < 12; u++) {                             \
    int tdy_ = u >> 2, cc_ = u & 3;                                            \
    DST[u] = (XWB)[(CBASE) + (size_t)(((tdy_ * 3 + (TDX)) * 4 + q) * 64 +      \
                                      cc_ * 16 + n16)];                        \
  }

// ---- one tdx phase: 8 B ds_reads + 48 MFMA using WREG ----
#define CONV_TDX(WREG, TDX)                                                    \
  {                                                                            \
    short8 bfr[2][4];                                                          \
    _Pragma("unroll") for (int sb = 0; sb < 2; sb++)                           \
      _Pragma("unroll") for (int r = 0; r < 4; r++)                            \
        bfr[sb][r] =                                                           \
            xx[q * 576 + (wv * 2 + sb) * 72 + r * 18 + (TDX) + n16];           \
    _Pragma("unroll") for (int tdy = 0; tdy < 3; tdy++) {                      \
      _Pragma("unroll") for (int cc = 0; cc < 4; cc++) {                       \
        _Pragma("unroll") for (int rg = 0; rg < 4; rg++)                       \
          acc[cc][rg] = __builtin_amdgcn_mfma_f32_16x16x32_bf16(               \
              WREG[tdy * 4 + cc], bfr[rg >> 1][(rg & 1) + tdy], acc[cc][rg],   \
              0, 0, 0);                                                        \
      }                                                                        \
    }                                                                          \
  }

// ---- K-loop body: X staged to LDS (9 gloads/thread); W batched into regs
// (wA,wB before the barrier — latency folds into the X vmcnt(0) drain;
// wC under tdx1 cover). R1 sync structure otherwise.
// needs: t, lane, wv, q, n16, xsrc, lds_x, acc[4][4] ----
#define CONV_MAIN_LOOP(INP, WBLOB, CB)                                         \
  {                                                                            \
    const short8* xwb = (const short8*)(WBLOB);                                \
    _Pragma("unroll 1") for (int ch = 0; ch < 8; ch++) {                       \
      if (ch) __syncthreads();                                                 \
      _Pragma("unroll") for (int k = 0; k < 9; k++)                            \
        gload_lds16((INP) + xsrc[k] + ch * 32,                                 \
                    lds_x + (size_t)(k * 256 + wv * 64) * 8);                  \
      const size_t cbase = (size_t)((CB) * 8 + ch) * 2304;                     \
      short8 wA[12], wB[12];                                                   \
      WLOAD(wA, xwb, cbase, 0)                                                 \
      WLOAD(wB, xwb, cbase, 1)                                                 \
      __syncthreads();                                                         \
      const short8* xx = (const short8*)lds_x;                                 \
      CONV_TDX(wA, 0)                                                          \
      short8 wC[12];                                                           \
      WLOAD(wC, xwb, cbase, 2)                                                 \
      CONV_TDX(wB, 1)                                                          \
      CONV_TDX(wC, 2)                                                          \
    }                                                                          \
  }

// ---- tower conv layer (bf16 in -> bf16 out, +bias, ReLU) ----
// XCD swizzle: p -> xcd=p&7, j=p>>3; cnt = 31 (xcd<4) else 30;
// j = tlw*4 + cb (cb fastest); tl = tlw*8 + xcd in [0,244);
// sblk = tl % 61, plane = tl / 61.
__global__ __launch_bounds__(256, 2) void conv_tower_mfma(
    const unsigned short* __restrict__ xin, unsigned short* __restrict__ xout,
    const unsigned short* __restrict__ wblob_cls,
    const unsigned short* __restrict__ wblob_box,
    const float* __restrict__ bias_cls, const float* __restrict__ bias_box,
    int in_n_stride, int in_tw_stride) {
  const int p = blockIdx.x;
  const int xcd = p & 7, jj = p >> 3;
  const int cnt = (xcd < 4) ? 31 : 30;
  if (jj >= 4 * cnt) return;
  const int tlw = jj >> 2, cb = jj & 3;
  const int tl = tlw * 8 + xcd;
  const int sblk = tl % 61;
  const int zpl = tl / 61;
  const int n = zpl >> 1, tw = zpl & 1;

  __shared__ __align__(16) unsigned short lds_x[18432];
  const int t = threadIdx.x, lane = t & 63, wv = t >> 6;
  const int q = lane >> 4, n16 = lane & 15;
  const unsigned short* wblob = tw ? wblob_box : wblob_cls;
  const float* bias = tw ? bias_box : bias_cls;
  const unsigned short* inp =
      xin + ((size_t)n * in_n_stride + (size_t)tw * in_tw_stride) * 256;
  unsigned short* outp = xout + ((size_t)(n * 2 + tw) * LVLTOT) * 256;

  floatx4 acc[4][4];
#pragma unroll
  for (int i = 0; i < 4; i++)
#pragma unroll
    for (int jx = 0; jx < 4; jx++) acc[i][jx] = (floatx4){0.f, 0.f, 0.f, 0.f};

  CONV_XPRE()
  CONV_MAIN_LOOP(inp, wblob, cb)

  // epilogue: +bias, relu, bf16, store 4 consecutive channels (8B) per lane
#pragma unroll
  for (int rg = 0; rg < 4; rg++) {
    int sg = sblk * 8 + wv * 2 + (rg >> 1);
    if (sg > 486) sg = 486;
    int l_, h0_, w0_, H_, Wp_, lo_;
    decode_seg(sg, l_, h0_, w0_, H_, Wp_, lo_);
    int h = h0_ + (rg & 1);
    int w_ = w0_ + n16;
    if (h < H_ && w_ < H_) {  // levels are square: W == H
#pragma unroll
      for (int cc = 0; cc < 4; cc++) {
        floatx4 bb = *(const floatx4*)(bias + cb * 64 + cc * 16 + q * 4);
        unsigned short pk[4];
#pragma unroll
        for (int rgi = 0; rgi < 4; rgi++)
          pk[rgi] = f2bf(fmaxf(acc[cc][rg][rgi] + bb[rgi], 0.f));
        size_t base = ((size_t)lo_ + (size_t)(h + 1) * Wp_ + (w_ + 1)) * 256 +
                      cb * 64 + cc * 16 + q * 4;
        *(unsigned long long*)(outp + base) = *(unsigned long long*)pk;
      }
    }
  }
}

// ---- merged final conv (yb<12: cls cb=yb; yb==12: box), permuted fp32 out --
// XCD swizzle: p -> xcd=p&7, j=p>>3; cnt = 16 (xcd<2) else 15;
// j = tlw*13 + yb (yb fastest); tl = tlw*8 + xcd in [0,122);
// sblk = tl % 61, n = tl / 61.
__global__ __launch_bounds__(256, 2) void conv_final_mfma(
    const unsigned short* __restrict__ xin, float* __restrict__ out,
    const unsigned short* __restrict__ wblob_cls,
    const unsigned short* __restrict__ wblob_box,
    const float* __restrict__ bias_cls, const float* __restrict__ bias_box) {
  const int p = blockIdx.x;
  const int xcd = p & 7, jj = p >> 3;
  const int cnt = (xcd < 2) ? 16 : 15;
  if (jj >= 13 * cnt) return;
  const int tlw = jj / 13, yb = jj - tlw * 13;
  const int tl = tlw * 8 + xcd;
  const int sblk = tl % 61;
  const int n = tl / 61;

  __shared__ __align__(16) unsigned short lds_x[18432];
  const int t = threadIdx.x, lane = t & 63, wv = t >> 6;
  const int q = lane >> 4, n16 = lane & 15;
  const bool is_cls = yb < 12;
  const int cb = is_cls ? yb : 0;
  const int tw = is_cls ? 0 : 1;
  const int Cout = is_cls ? 720 : 36;
  const unsigned short* wblob = is_cls ? wblob_cls : wblob_box;
  const float* bias = is_cls ? bias_cls : bias_box;
  const int RB[5] = {0, 90000, 112500, 118125, 119646};
  const unsigned short* inp = xin + ((size_t)(n * 2 + tw) * LVLTOT) * 256;

  floatx4 acc[4][4];
#pragma unroll
  for (int i = 0; i < 4; i++)
#pragma unroll
    for (int jx = 0; jx < 4; jx++) acc[i][jx] = (floatx4){0.f, 0.f, 0.f, 0.f};

  CONV_XPRE()
  CONV_MAIN_LOOP(inp, wblob, cb)

#pragma unroll
  for (int rg = 0; rg < 4; rg++) {
    int sg = sblk * 8 + wv * 2 + (rg >> 1);
    if (sg > 486) sg = 486;
    int l_, h0_, w0_, H_, Wp_, lo_;
    decode_seg(sg, l_, h0_, w0_, H_, Wp_, lo_);
    int h = h0_ + (rg & 1);
    int w_ = w0_ + n16;
    if (h < H_ && w_ < H_) {
      size_t ridx = (size_t)RB[l_] + ((size_t)h * H_ + w_) * 9;
#pragma unroll
      for (int cc = 0; cc < 4; cc++) {
        int co0 = cb * 64 + cc * 16 + q * 4;
        if (co0 >= Cout) continue;
        floatx4 bb = *(const floatx4*)(bias + co0);
        int a = is_cls ? (co0 / 80) : (co0 >> 2);
        int col0 = is_cls ? (co0 - a * 80) : 80;
        floatx4 v;
#pragma unroll
        for (int rgi = 0; rgi < 4; rgi++) v[rgi] = acc[cc][rg][rgi] + bb[rgi];
        *(floatx4*)(out + ((size_t)n * 120087 + ridx + a) * 84 + col0) = v;
      }
    }
  }
}

extern "C" void kernel_launch(void* const* d_in, const int* in_sizes, int n_in,
                              void* d_out, int out_size, void* d_ws,
                              size_t ws_size, hipStream_t stream) {
  // ws layout (bytes):
  //   bufB [0, 28964864)    (X0 aliased to bufB planes 2,3: dead after layer 1)
  //   X0   [14482432, 28964864)
  //   bufA [28964864, 57929728)
  //   tower blobs 8 x 1179648 at 57929728 (cls0..3, box0..3)
  //   cls final blob 3538944 at 67366912; box final blob 294912 at 70905856
  char* ws = (char*)d_ws;
  unsigned short* bufB = (unsigned short*)(ws);
  unsigned short* X0 = (unsigned short*)(ws + 14482432);
  unsigned short* bufA = (unsigned short*)(ws + 28964864);
  unsigned short* tb[8];
  for (int i = 0; i < 8; i++)
    tb[i] = (unsigned short*)(ws + 57929728 + (size_t)i * 1179648);
  unsigned short* fb_cls = (unsigned short*)(ws + 67366912);
  unsigned short* fb_box = (unsigned short*)(ws + 70905856);

  float* out = (float*)d_out;

  PrepArgs pa;
  for (int i = 0; i < 5; i++) pa.f[i] = (const float*)d_in[i];
  for (int i = 0; i < 4; i++) {
    pa.w[i] = (const float*)d_in[5 + 2 * i];       // cls_w0..3
    pa.w[4 + i] = (const float*)d_in[13 + 2 * i];  // box_w0..3
    pa.wdst[i] = tb[i];
    pa.wdst[4 + i] = tb[4 + i];
    pa.cout[i] = pa.cout[4 + i] = 256;
  }
  pa.w[8] = (const float*)d_in[21]; pa.wdst[8] = fb_cls; pa.cout[8] = 720;
  pa.w[9] = (const float*)d_in[23]; pa.wdst[9] = fb_box; pa.cout[9] = 36;
  // padded-co block counts: towers 256 each, cls 768, box 64
  int off = 0;
  for (int i = 0; i < 8; i++) { pa.wblk_off[i] = off; off += 256; }
  pa.wblk_off[8] = off; off += 768;
  pa.wblk_off[9] = off; off += 64;
  pa.wblk_off[10] = off;  // 2880
  pa.x0 = X0;
  pa.bufA = bufA;
  pa.bufB = bufB;

  prep<<<dim3(4770), 256, 0, stream>>>(pa);

  const float *cls_b[4], *box_b[4];
  for (int i = 0; i < 4; i++) {
    cls_b[i] = (const float*)d_in[6 + 2 * i];
    box_b[i] = (const float*)d_in[14 + 2 * i];
  }

  conv_tower_mfma<<<dim3(992), 256, 0, stream>>>(X0, bufA, tb[0], tb[4],
                                                 cls_b[0], box_b[0], LVLTOT, 0);
  conv_tower_mfma<<<dim3(992), 256, 0, stream>>>(
      bufA, bufB, tb[1], tb[5], cls_b[1], box_b[1], 2 * LVLTOT, LVLTOT);
  conv_tower_mfma<<<dim3(992), 256, 0, stream>>>(
      bufB, bufA, tb[2], tb[6], cls_b[2], box_b[2], 2 * LVLTOT, LVLTOT);
  conv_tower_mfma<<<dim3(992), 256, 0, stream>>>(
      bufA, bufB, tb[3], tb[7], cls_b[3], box_b[3], 2 * LVLTOT, LVLTOT);

  conv_final_mfma<<<dim3(1664), 256, 0, stream>>>(
      bufB, out, fb_cls, fb_box, (const float*)d_in[22], (const float*)d_in[24]);
}